// Round 3
// baseline (429.280 us; speedup 1.0000x reference)
//
#include <hip/hip_runtime.h>

#define NN 4096      // reviews
#define LL 128       // tokens
#define DD 200       // word dim
#define AA 32        // aspects
#define NEG 5
#define BB 1024      // users/items
#define FF 16384     // B*H flat history

// workspace layout (float offsets)
#define WS_RS    0
#define WS_Y     (NN*DD)
#define WS_USUM  (WS_Y + NN*DD)
#define WS_ISUM  (WS_USUM + BB*DD)
#define WS_UCNT  (WS_ISUM + BB*DD)
#define WS_ICNT  (WS_UCNT + BB)
#define WS_ACC   (WS_ICNT + BB)           // [0]=J_sum [1]=U_mean [2]=RL_sum [8]=done-counter(int)
#define WS_TT    (WS_ACC + 16)            // transposed T (32 x 200)

// ---------------- DPP reductions (VALU, no DS pipe) -------------------------
// ctrl: 0xB1 quad_perm[1,0,3,2], 0x4E quad_perm[2,3,0,1], 0x124 row_ror:4,
//       0x128 row_ror:8, 0x142 row_bcast15, 0x143 row_bcast31
template<int C, int RM>
__device__ __forceinline__ float dpp_add(float v){
  int t = __builtin_amdgcn_update_dpp(0, __float_as_int(v), C, RM, 0xf, false);
  return v + __int_as_float(t);
}
template<int C, int RM>
__device__ __forceinline__ float dpp_fmax(float v){
  int t = __builtin_amdgcn_update_dpp(__float_as_int(-3.0e38f), __float_as_int(v),
                                      C, RM, 0xf, false);
  return fmaxf(v, __int_as_float(t));
}
// full 64-lane sum; valid in lanes 48..63 (use lane 63)
__device__ __forceinline__ float sum64(float v){
  v = dpp_add<0xB1, 0xF>(v);
  v = dpp_add<0x4E, 0xF>(v);
  v = dpp_add<0x124,0xF>(v);
  v = dpp_add<0x128,0xF>(v);
  v = dpp_add<0x142,0xA>(v);
  v = dpp_add<0x143,0xC>(v);
  return v;
}
__device__ __forceinline__ float max64(float v){
  v = dpp_fmax<0xB1, 0xF>(v);
  v = dpp_fmax<0x4E, 0xF>(v);
  v = dpp_fmax<0x124,0xF>(v);
  v = dpp_fmax<0x128,0xF>(v);
  v = dpp_fmax<0x142,0xA>(v);
  v = dpp_fmax<0x143,0xC>(v);
  return v;
}
// per-32-lane-half sums; lower-half sum valid in lanes 16..31, upper in 48..63
__device__ __forceinline__ float sum32h(float v){
  v = dpp_add<0xB1, 0xF>(v);
  v = dpp_add<0x4E, 0xF>(v);
  v = dpp_add<0x124,0xF>(v);
  v = dpp_add<0x128,0xF>(v);
  v = dpp_add<0x142,0xA>(v);
  return v;
}
__device__ __forceinline__ float rdlane(float v, int l){
  return __int_as_float(__builtin_amdgcn_readlane(__float_as_int(v), l));
}

// ---- prep: Y = rev_pos @ M (512 blocks x 8 reviews) + T transpose (block 512)
__global__ __launch_bounds__(256)
void k_prep(const float* __restrict__ rp, const float* __restrict__ M,
            const float* __restrict__ T_w,
            float* __restrict__ Y, float* __restrict__ Tt){
  int t = threadIdx.x;
  if (blockIdx.x == 512){
    for (int i = t; i < DD * AA; i += 256){
      int d = i >> 5, a = i & 31;
      Tt[a * DD + d] = T_w[i];
    }
    return;
  }
  __shared__ float rpl[8 * DD];
  int n0 = blockIdx.x * 8;
  for (int i = t; i < 8 * DD; i += 256) rpl[i] = rp[(size_t)n0 * DD + i];
  __syncthreads();
  if (t < DD){
    float acc[8];
#pragma unroll
    for (int i = 0; i < 8; ++i) acc[i] = 0.f;
    for (int d = 0; d < DD; d += 4){
      float m0 = M[(d    ) * DD + t];
      float m1 = M[(d + 1) * DD + t];
      float m2 = M[(d + 2) * DD + t];
      float m3 = M[(d + 3) * DD + t];
#pragma unroll
      for (int i = 0; i < 8; ++i)
        acc[i] += rpl[i*DD+d]*m0 + rpl[i*DD+d+1]*m1 + rpl[i*DD+d+2]*m2 + rpl[i*DD+d+3]*m3;
    }
#pragma unroll
    for (int i = 0; i < 8; ++i) Y[(size_t)(n0 + i) * DD + t] = acc[i];
  }
}

// ---- main per-review kernel (+ U-loss block at blockIdx == NN) -------------
// main-path LDS (floats): y_l[0,200) dxax[208,336) zsm[336,536) r_l[536,736)
//                         lsps[736,768) sc[768,776) hrowl(int)[776,904)
// uloss-path LDS: Tl[0,6464) stride 202, nrm[6464,6496), wred[6496,6500)
__global__ __launch_bounds__(256, 6)
void k_main(const int* __restrict__ hist, const float* __restrict__ Yg,
            const float* __restrict__ rev_neg, const float* __restrict__ word_emb,
            const float* __restrict__ W_w, const float* __restrict__ W_b,
            const float* __restrict__ Tt, const float* __restrict__ T_w,
            float* __restrict__ rs_out, float* __restrict__ acc)
{
  __shared__ __align__(16) float smem[6504];
  const int t = threadIdx.x;
  const int w = t >> 6, j = t & 63;

  if (blockIdx.x == NN){
    // ================= U loss =================
    float* Tl  = smem;          // [32][202]
    float* nrm = smem + 6464;
    float* wred= smem + 6496;
    for (int i = t; i < DD * AA; i += 256){
      int d = i >> 5, a = i & 31;
      Tl[a * 202 + d] = T_w[i];
    }
    __syncthreads();
    if (t < AA){
      float s = 0.f;
      for (int d = 0; d < DD; d += 2){
        float2 v = *(float2*)&Tl[t * 202 + d];
        s += v.x * v.x + v.y * v.y;
      }
      nrm[t] = fmaxf(sqrtf(s), 1e-12f);
    }
    __syncthreads();
    int a = t >> 3, b0 = (t & 7) * 4;
    float d0 = 0, d1 = 0, d2 = 0, d3 = 0;
    for (int d = 0; d < DD; d += 2){
      float2 va = *(float2*)&Tl[a * 202 + d];
      float2 v0 = *(float2*)&Tl[(b0    ) * 202 + d];
      float2 v1 = *(float2*)&Tl[(b0 + 1) * 202 + d];
      float2 v2 = *(float2*)&Tl[(b0 + 2) * 202 + d];
      float2 v3 = *(float2*)&Tl[(b0 + 3) * 202 + d];
      d0 += va.x * v0.x + va.y * v0.y;
      d1 += va.x * v1.x + va.y * v1.y;
      d2 += va.x * v2.x + va.y * v2.y;
      d3 += va.x * v3.x + va.y * v3.y;
    }
    float na = nrm[a], gg = 0.f, g;
    g = d0 / (na * nrm[b0    ]) - (a == b0     ? 1.f : 0.f); gg += g * g;
    g = d1 / (na * nrm[b0 + 1]) - (a == b0 + 1 ? 1.f : 0.f); gg += g * g;
    g = d2 / (na * nrm[b0 + 2]) - (a == b0 + 2 ? 1.f : 0.f); gg += g * g;
    g = d3 / (na * nrm[b0 + 3]) - (a == b0 + 3 ? 1.f : 0.f); gg += g * g;
    float v = sum64(gg);
    if (j == 63) wred[w] = v;
    __syncthreads();
    if (t == 0) acc[1] = (wred[0] + wred[1] + wred[2] + wred[3]) / (float)(AA * AA);
    return;
  }

  // ================= per-review path =================
  float* y_l  = smem;
  float* dxax = smem + 208;
  float* zsm  = smem + 336;
  float* r_l  = smem + 536;
  float* lsps = smem + 736;
  float* sc   = smem + 768;
  int*   hrowl= (int*)(smem + 776);

  const int n = blockIdx.x;
  if (t < DD) y_l[t] = Yg[(size_t)n * DD + t];
  if (t < LL) hrowl[t] = hist[(size_t)n * LL + t];
  __syncthreads();

  // ---- dx[l] = dot(e_w[l], y): wave per row, stream from global -----------
  float4 y4 = make_float4(0.f, 0.f, 0.f, 0.f);
  if (j < 50) y4 = *(const float4*)(y_l + 4 * j);
#pragma unroll 4
  for (int k = 0; k < 32; ++k){
    int l = k * 4 + w;
    float p = 0.f;
    if (j < 50){
      int row = hrowl[l];
      float4 g = *(const float4*)(word_emb + (size_t)row * DD + 4 * j);
      p = g.x * y4.x + g.y * y4.y + g.z * y4.z + g.w * y4.w;
    }
    float v = sum64(p);
    if (j == 63) dxax[l] = v;
  }
  __syncthreads();

  // ---- softmax over 128 logits (wave 0) -----------------------------------
  if (w == 0){
    float a0 = dxax[j], a1 = dxax[j + 64];
    float M = rdlane(max64(fmaxf(a0, a1)), 63);
    float e0 = __expf(a0 - M), e1 = __expf(a1 - M);
    float S = rdlane(sum64(e0 + e1), 63);
    float inv = 1.f / S;
    dxax[j] = e0 * inv; dxax[j + 64] = e1 * inv;
  }
  __syncthreads();

  // ---- z[d2] = sum_l2 flat[d2*128+l2]*ax[l2] ------------------------------
  {
    const int h = j >> 5, jq = j & 31;
    float4 ax4 = ((const float4*)dxax)[jq];
#pragma unroll 2
    for (int k = 0; k < 25; ++k){
      int d2 = k * 8 + w * 2 + h;
      unsigned f = (unsigned)d2 * 128u + 4u * (unsigned)jq;
      unsigned r = f / 200u;
      unsigned c = f - r * 200u;
      int row = hrowl[r];
      float4 g = *(const float4*)(word_emb + (size_t)row * DD + c);
      float p = g.x * ax4.x + g.y * ax4.y + g.z * ax4.z + g.w * ax4.w;
      float v = sum32h(p);
      if ((j & 31) == 31) zsm[d2] = v;
    }
  }
  __syncthreads();

  // ---- aspect logits: wave w computes a = w*8..w*8+7 ----------------------
#pragma unroll
  for (int aa = 0; aa < 8; ++aa){
    int a = w * 8 + aa;
    const float* Wr = W_w + a * DD;
    float p = zsm[j] * Wr[j] + zsm[j + 64] * Wr[j + 64] + zsm[j + 128] * Wr[j + 128];
    if (j < 8) p += zsm[j + 192] * Wr[j + 192];
    float v = sum64(p);
    if (j == 63) lsps[a] = v + W_b[a];
  }
  __syncthreads();

  // ---- softmax over 32 aspects (wave 0) -----------------------------------
  if (w == 0){
    float v = (j < 32) ? lsps[j] : -3.0e38f;
    float M = rdlane(max64(v), 63);
    float e = __expf(v - M);
    float S = rdlane(sum64(e), 63);
    if (j < 32) lsps[j] = e / S;
  }
  __syncthreads();

  // ---- r_s[d] = sum_a p[a]*T[d][a] via transposed Tt ----------------------
  if (t < DD){
    float a = 0.f;
#pragma unroll
    for (int q = 0; q < AA; ++q) a += lsps[q] * Tt[q * DD + t];
    r_l[t] = a;
    rs_out[(size_t)n * DD + t] = a;
  }
  __syncthreads();

  // ---- c1 = cos(r, z) (wave 0, float4) ------------------------------------
  if (w == 0){
    float rr = 0, zz = 0, rz = 0;
    if (j < 50){
      float4 rv = *(float4*)(r_l + 4 * j);
      float4 zv = *(float4*)(zsm + 4 * j);
      rr = rv.x*rv.x + rv.y*rv.y + rv.z*rv.z + rv.w*rv.w;
      zz = zv.x*zv.x + zv.y*zv.y + zv.z*zv.z + zv.w*zv.w;
      rz = rv.x*zv.x + rv.y*zv.y + rv.z*zv.z + rv.w*zv.w;
    }
    rr = rdlane(sum64(rr), 63); zz = rdlane(sum64(zz), 63); rz = rdlane(sum64(rz), 63);
    if (j == 0){
      float nr = fmaxf(sqrtf(rr), 1e-12f);
      float nz = fmaxf(sqrtf(zz), 1e-12f);
      sc[0] = rz / (nr * nz);          // c1
      sc[1] = nr;
    }
  }
  __syncthreads();

  // ---- c2 over 5 negatives (waves 0..3; wave 0 also #4), float4 -----------
  for (int g5 = w; g5 < NEG; g5 += 4){
    const float* neg = rev_neg + ((size_t)n * NEG + g5) * DD;
    float nn = 0, dr = 0;
    if (j < 50){
      float4 v = *(const float4*)(neg + 4 * j);
      float4 rv = *(float4*)(r_l + 4 * j);
      nn = v.x*v.x + v.y*v.y + v.z*v.z + v.w*v.w;
      dr = v.x*rv.x + v.y*rv.y + v.z*rv.z + v.w*rv.w;
    }
    nn = rdlane(sum64(nn), 63); dr = rdlane(sum64(dr), 63);
    if (j == 0){
      float c2 = dr / (fmaxf(sqrtf(nn), 1e-12f) * sc[1]);
      sc[2 + g5] = fmaxf(0.f, c2 - sc[0]);
    }
  }
  __syncthreads();
  if (t == 0) atomicAdd(&acc[0], sc[2] + sc[3] + sc[4] + sc[5] + sc[6]);
}

// ---- segment mean scatter (run-length compressed atomics) ------------------
__device__ __forceinline__ void seg_side(const int* __restrict__ idx, const int* __restrict__ seg,
                                         const float* __restrict__ rs,
                                         float* __restrict__ sum, float* __restrict__ cnt,
                                         int f0, int t){
  int cur = seg[f0];
  float acc = 0.f; int c = 0;
  for (int k = 0; k < 16; ++k){
    int f = f0 + k;
    int s = seg[f];
    if (s != cur){
      if (t < DD) atomicAdd(&sum[(size_t)cur * DD + t], acc);
      if (t == 0) atomicAdd(&cnt[cur], (float)c);
      acc = 0.f; c = 0; cur = s;
    }
    if (t < DD) acc += rs[(size_t)idx[f] * DD + t];
    c++;
  }
  if (t < DD) atomicAdd(&sum[(size_t)cur * DD + t], acc);
  if (t == 0) atomicAdd(&cnt[cur], (float)c);
}

__global__ __launch_bounds__(256)
void k_seg(const int* __restrict__ u_idx, const int* __restrict__ u_seg,
           const int* __restrict__ i_idx, const int* __restrict__ i_seg,
           const float* __restrict__ rs,
           float* __restrict__ u_sum, float* __restrict__ u_cnt,
           float* __restrict__ i_sum, float* __restrict__ i_cnt){
  int t = threadIdx.x;
  int f0 = blockIdx.x * 16;
  seg_side(u_idx, u_seg, rs, u_sum, u_cnt, f0, t);
  seg_side(i_idx, i_seg, rs, i_sum, i_cnt, f0, t);
}

// ---- rating loss + fused finalization (last block writes d_out) ------------
__global__ __launch_bounds__(64)
void k_rating(const float* __restrict__ u_sum, const float* __restrict__ u_cnt,
              const float* __restrict__ i_sum, const float* __restrict__ i_cnt,
              const float* __restrict__ label, float* __restrict__ acc,
              float* __restrict__ out){
  int b = blockIdx.x, j = threadIdx.x;
  float d = 0.f;
  if (j < 50){
    float4 u = *(const float4*)(u_sum + (size_t)b * DD + 4 * j);
    float4 i = *(const float4*)(i_sum + (size_t)b * DD + 4 * j);
    d = u.x*i.x + u.y*i.y + u.z*i.z + u.w*i.w;
  }
  d = rdlane(sum64(d), 63);
  if (j == 0){
    float pred = d / (u_cnt[b] * i_cnt[b]) + 3.5f;
    float e = pred - label[b];
    atomicAdd(&acc[2], e * e);
    __threadfence();
    int prev = atomicAdd((int*)(acc + 8), 1);
    if (prev == BB - 1){
      float R = atomicAdd(&acc[2], 0.f) / (float)BB;   // coherent read
      float J = acc[0] / (float)(NN * NEG);
      float U = acc[1];
      float abae = U + J;
      out[0] = R + abae;
      out[1] = R;
      out[2] = abae;
    }
  }
}

extern "C" void kernel_launch(void* const* d_in, const int* in_sizes, int n_in,
                              void* d_out, int out_size, void* d_ws, size_t ws_size,
                              hipStream_t stream){
  const int*   hist     = (const int*)  d_in[0];
  const float* rev_pos  = (const float*)d_in[1];
  const float* rev_neg  = (const float*)d_in[2];
  const float* label    = (const float*)d_in[5];
  const int*   u_idx    = (const int*)  d_in[6];
  const int*   u_seg    = (const int*)  d_in[7];
  const int*   i_idx    = (const int*)  d_in[8];
  const int*   i_seg    = (const int*)  d_in[9];
  const float* word_emb = (const float*)d_in[10];
  const float* M_w      = (const float*)d_in[11];
  const float* W_w      = (const float*)d_in[12];
  const float* W_b      = (const float*)d_in[13];
  const float* T_w      = (const float*)d_in[14];

  float* ws   = (float*)d_ws;
  float* rs   = ws + WS_RS;
  float* Yg   = ws + WS_Y;
  float* usum = ws + WS_USUM;
  float* isum = ws + WS_ISUM;
  float* ucnt = ws + WS_UCNT;
  float* icnt = ws + WS_ICNT;
  float* accp = ws + WS_ACC;
  float* Tt   = ws + WS_TT;

  // zero seg sums/cnts + accumulators (+ done counter)
  hipMemsetAsync(usum, 0, (size_t)(WS_TT - WS_USUM) * sizeof(float), stream);

  k_prep<<<513, 256, 0, stream>>>(rev_pos, M_w, T_w, Yg, Tt);
  k_main<<<NN + 1, 256, 0, stream>>>(hist, Yg, rev_neg, word_emb, W_w, W_b,
                                     Tt, T_w, rs, accp);
  k_seg<<<FF / 16, 256, 0, stream>>>(u_idx, u_seg, i_idx, i_seg, rs,
                                     usum, ucnt, isum, icnt);
  k_rating<<<BB, 64, 0, stream>>>(usum, ucnt, isum, icnt, label, accp,
                                  (float*)d_out);
}